// Round 3
// baseline (433.372 us; speedup 1.0000x reference)
//
#include <hip/hip_runtime.h>
#include <hip/hip_bf16.h>
#include <math.h>

#define DIM 768
#define NH 12
#define HD 64
#define NQ 1024
#define NKV 4096

typedef __attribute__((ext_vector_type(4))) float f32x4;
typedef __attribute__((ext_vector_type(8))) __bf16 bf16x8;
typedef __attribute__((ext_vector_type(8))) unsigned short u16x8;
typedef unsigned short u16;

typedef const __attribute__((address_space(1))) void* gas_t;
typedef __attribute__((address_space(3))) void* las_t;

__device__ __forceinline__ void gl16(const void* g, void* l) {
    __builtin_amdgcn_global_load_lds((gas_t)g, (las_t)l, 16, 0, 0);
}

__device__ __forceinline__ u16 f2b(float x) {
    __bf16 h = (__bf16)x;
    return __builtin_bit_cast(u16, h);
}

__device__ __forceinline__ f32x4 mfma16(const u16* a, const u16* b, f32x4 c) {
    bf16x8 av = *reinterpret_cast<const bf16x8*>(a);
    bf16x8 bv = *reinterpret_cast<const bf16x8*>(b);
    return __builtin_amdgcn_mfma_f32_16x16x32_bf16(av, bv, c, 0, 0, 0);
}

// ---------------- cast f32 -> bf16 (8 elems/thread) ----------------
__global__ __launch_bounds__(256) void cast_bf16_kernel(
    const float* __restrict__ in, u16* __restrict__ out, int n8)
{
    int i = blockIdx.x * 256 + threadIdx.x;
    if (i >= n8) return;
    const float4* p = reinterpret_cast<const float4*>(in) + (size_t)i * 2;
    float4 a = p[0], b = p[1];
    u16x8 o;
    o[0] = f2b(a.x); o[1] = f2b(a.y); o[2] = f2b(a.z); o[3] = f2b(a.w);
    o[4] = f2b(b.x); o[5] = f2b(b.y); o[6] = f2b(b.z); o[7] = f2b(b.w);
    reinterpret_cast<u16x8*>(out)[i] = o;
}

// ---------------- transpose+cast W[K][N] f32 -> Wt[N][K] bf16 ----------------
__global__ __launch_bounds__(256) void transpose_cast_kernel(
    const float* __restrict__ W, u16* __restrict__ Wt, int K, int N)
{
    __shared__ u16 T[64][72];
    int k0 = blockIdx.y * 64, n0 = blockIdx.x * 64;
    int tid = threadIdx.x;
    int r = tid >> 2, c = (tid & 3) * 16;
    const float* src = W + (size_t)(k0 + r) * N + n0 + c;
    #pragma unroll
    for (int j = 0; j < 16; j += 4) {
        float4 f = *reinterpret_cast<const float4*>(src + j);
        T[r][c + j + 0] = f2b(f.x); T[r][c + j + 1] = f2b(f.y);
        T[r][c + j + 2] = f2b(f.z); T[r][c + j + 3] = f2b(f.w);
    }
    __syncthreads();
    int d = tid >> 2, c2 = (tid & 3) * 16;
    u16x8 o0, o1;
    #pragma unroll
    for (int j = 0; j < 8; ++j) o0[j] = T[c2 + j][d];
    #pragma unroll
    for (int j = 0; j < 8; ++j) o1[j] = T[c2 + 8 + j][d];
    u16* dst = Wt + (size_t)(n0 + d) * K + k0 + c2;
    *reinterpret_cast<u16x8*>(dst) = o0;
    *reinterpret_cast<u16x8*>(dst + 8) = o1;
}

// ---------------- transpose V part of kv into vt[bh][d][kv] ----------------
__global__ __launch_bounds__(256) void transpose_v_kernel(
    const u16* __restrict__ kv, u16* __restrict__ vt)
{
    __shared__ u16 T[64][72];
    int kvt = blockIdx.x, bh = blockIdx.y;
    int bb = bh / NH, h = bh % NH;
    int tid = threadIdx.x;
    int r = tid >> 2, c = (tid & 3) * 16;
    const u16* src = kv + (size_t)(bb * NKV + kvt * 64 + r) * (2 * DIM) + DIM + h * HD + c;
    u16x8 v0 = *reinterpret_cast<const u16x8*>(src);
    u16x8 v1 = *reinterpret_cast<const u16x8*>(src + 8);
    #pragma unroll
    for (int j = 0; j < 8; ++j) T[r][c + j] = v0[j];
    #pragma unroll
    for (int j = 0; j < 8; ++j) T[r][c + 8 + j] = v1[j];
    __syncthreads();
    int d = tid >> 2, c2 = (tid & 3) * 16;
    u16x8 o0, o1;
    #pragma unroll
    for (int j = 0; j < 8; ++j) o0[j] = T[c2 + j][d];
    #pragma unroll
    for (int j = 0; j < 8; ++j) o1[j] = T[c2 + 8 + j][d];
    u16* dst = vt + ((size_t)bh * HD + d) * NKV + kvt * 64 + c2;
    *reinterpret_cast<u16x8*>(dst) = o0;
    *reinterpret_cast<u16x8*>(dst + 8) = o1;
}

// ---------------- LayerNorm (row = 768), f32 in -> bf16 out ----------------
__global__ __launch_bounds__(256) void ln_kernel(
    const float* __restrict__ x, const float* __restrict__ w,
    const float* __restrict__ b, u16* __restrict__ out)
{
    int row = blockIdx.x;
    const float* xr = x + (size_t)row * DIM;
    int tid = threadIdx.x;
    float v0 = xr[tid], v1 = xr[tid + 256], v2 = xr[tid + 512];
    float s = v0 + v1 + v2;
    float s2 = v0 * v0 + v1 * v1 + v2 * v2;
    for (int off = 1; off < 64; off <<= 1) {
        s += __shfl_xor(s, off);
        s2 += __shfl_xor(s2, off);
    }
    __shared__ float ss[4], ss2[4];
    int wid = tid >> 6, lane = tid & 63;
    if (lane == 0) { ss[wid] = s; ss2[wid] = s2; }
    __syncthreads();
    s = ss[0] + ss[1] + ss[2] + ss[3];
    s2 = ss2[0] + ss2[1] + ss2[2] + ss2[3];
    float mu = s * (1.0f / DIM);
    float var = s2 * (1.0f / DIM) - mu * mu;
    float r = rsqrtf(var + 1e-5f);
    u16* orow = out + (size_t)row * DIM;
    orow[tid]       = f2b((v0 - mu) * r * w[tid]       + b[tid]);
    orow[tid + 256] = f2b((v1 - mu) * r * w[tid + 256] + b[tid + 256]);
    orow[tid + 512] = f2b((v2 - mu) * r * w[tid + 512] + b[tid + 512]);
}

// ---------------- GEMM 128x128 tile: C = A[M,K] @ Bt[N,K]^T + bias ----------------
// 1D grid = (N/128)*(M/128), XCD-swizzled: blocks sharing an A-panel (same m0)
// land on the same XCD. Requires (M/128) % 8 == 0.
// EPI 0: bf16 out   EPI 1: bf16 out * 0.125   EPI 2: f32 out + res   EPI 3: bf16 gelu
template <int EPI>
__global__ __launch_bounds__(256) void gemm_kernel(
    const u16* __restrict__ A, const u16* __restrict__ Bt,
    const float* __restrict__ bias, const float* __restrict__ res,
    void* __restrict__ out, int M, int N, int K)
{
    __shared__ u16 As[4096]; // 128 rows x 32 k, 16B chunks XOR-swizzled by row&3
    __shared__ u16 Bs[4096];
    int p = blockIdx.x;
    int nbx = N >> 7;
    int ypx = (M >> 7) >> 3;
    int xcd = p & 7, slot = p >> 3;
    int by = xcd * ypx + slot / nbx;
    int bx = slot - (slot / nbx) * nbx;
    int n0 = bx * 128, m0 = by * 128;
    int tid = threadIdx.x, lane = tid & 63, wave = tid >> 6;
    int wm = (wave >> 1) * 64, wn = (wave & 1) * 64;
    f32x4 acc[4][4] = {};

    int r0 = tid >> 2;
    int c0 = ((tid & 3) ^ (r0 & 3)) * 8;
    const u16* ap0 = A + (size_t)(m0 + r0) * K + c0;
    const u16* ap1 = A + (size_t)(m0 + r0 + 64) * K + c0;
    const u16* bp0 = Bt + (size_t)(n0 + r0) * K + c0;
    const u16* bp1 = Bt + (size_t)(n0 + r0 + 64) * K + c0;
    u16* la0 = As + wave * 512;
    u16* la1 = As + 2048 + wave * 512;
    u16* lb0 = Bs + wave * 512;
    u16* lb1 = Bs + 2048 + wave * 512;

    int fr = lane & 15, fq = lane >> 4;
    int fsw = (fq ^ (lane & 3)) * 8;

    for (int k0 = 0; k0 < K; k0 += 32) {
        __syncthreads();
        gl16(ap0, la0); gl16(ap1, la1); gl16(bp0, lb0); gl16(bp1, lb1);
        ap0 += 32; ap1 += 32; bp0 += 32; bp1 += 32;
        __syncthreads();
        #pragma unroll
        for (int mf = 0; mf < 4; ++mf) {
            const u16* ap = As + (wm + mf * 16 + fr) * 32 + fsw;
            #pragma unroll
            for (int nf = 0; nf < 4; ++nf)
                acc[mf][nf] = mfma16(ap, Bs + (wn + nf * 16 + fr) * 32 + fsw, acc[mf][nf]);
        }
    }

    float* outf = reinterpret_cast<float*>(out);
    u16* outb = reinterpret_cast<u16*>(out);
    #pragma unroll
    for (int mf = 0; mf < 4; ++mf)
        #pragma unroll
        for (int nf = 0; nf < 4; ++nf)
            #pragma unroll
            for (int r = 0; r < 4; ++r) {
                int row = m0 + wm + mf * 16 + fq * 4 + r;
                int col = n0 + wn + nf * 16 + fr;
                size_t idx = (size_t)row * N + col;
                float v = acc[mf][nf][r] + bias[col];
                if constexpr (EPI == 0) {
                    outb[idx] = f2b(v);
                } else if constexpr (EPI == 1) {
                    outb[idx] = f2b(v * 0.125f);
                } else if constexpr (EPI == 2) {
                    outf[idx] = v + res[idx];
                } else {
                    float g = 0.5f * v * (1.0f + erff(v * 0.70710678118f));
                    outb[idx] = f2b(g);
                }
            }
}

// ---------------- Fused flash attention: QBLK=32, KVBLK=64, 4 waves ----------------
// grid 1536 (1D), XCD-swizzled: 6 bh per XCD, q-tiles of a bh stay on one XCD.
// Next-iteration K/V register fragments prefetched (latency hidden under compute).
__global__ __launch_bounds__(256) void attn_kernel(
    const u16* __restrict__ q, const u16* __restrict__ kv,
    const u16* __restrict__ vt, u16* __restrict__ o)
{
    int p = blockIdx.x;
    int xcd = p & 7, slot = p >> 3;        // slot in [0,192)
    int bh = xcd * 6 + (slot >> 5);
    int qt = slot & 31;                    // 32 q-tiles of 32 rows
    int h = bh % NH, bb = bh / NH;

    __shared__ float S[32][68];
    __shared__ u16 P[32 * 64];             // 16B chunks swizzled by row&7
    __shared__ float mrow[32], lrow[32], arow[32];

    int tid = threadIdx.x, lane = tid & 63, wave = tid >> 6;
    int fr = lane & 15, fq = lane >> 4;

    // Q fragments in registers (rows mf*16+fr of this q-tile)
    bf16x8 qf[2][2];
    const u16* qbase = q + (size_t)(bb * NQ + qt * 32) * DIM + h * HD + fq * 8;
    #pragma unroll
    for (int mf = 0; mf < 2; ++mf)
        #pragma unroll
        for (int ks = 0; ks < 2; ++ks)
            qf[mf][ks] = *reinterpret_cast<const bf16x8*>(
                qbase + (size_t)(mf * 16 + fr) * DIM + ks * 32);

    if (tid < 32) { mrow[tid] = -1e30f; lrow[tid] = 0.f; }

    f32x4 oacc[2] = {};

    const u16* kptr = kv + (size_t)(bb * NKV + wave * 16 + fr) * (2 * DIM) + h * HD + fq * 8;
    const u16* vptr = vt + ((size_t)bh * HD + wave * 16 + fr) * NKV + fq * 8;

    bf16x8 kf0 = *reinterpret_cast<const bf16x8*>(kptr);
    bf16x8 kf1 = *reinterpret_cast<const bf16x8*>(kptr + 32);
    bf16x8 vf0 = *reinterpret_cast<const bf16x8*>(vptr);
    bf16x8 vf1 = *reinterpret_cast<const bf16x8*>(vptr + 32);

    for (int it = 0; it < NKV / 64; ++it) {
        // issue next-tile K/V loads (unconditional; one-tile overrun stays in ws)
        kptr += (size_t)64 * 2 * DIM;
        vptr += 64;
        bf16x8 nk0 = *reinterpret_cast<const bf16x8*>(kptr);
        bf16x8 nk1 = *reinterpret_cast<const bf16x8*>(kptr + 32);
        bf16x8 nv0 = *reinterpret_cast<const bf16x8*>(vptr);
        bf16x8 nv1 = *reinterpret_cast<const bf16x8*>(vptr + 32);

        // ---- QK^T: wave computes S[:, wave*16 .. +16] ----
        f32x4 s[2] = {};
        #pragma unroll
        for (int mf = 0; mf < 2; ++mf) {
            s[mf] = __builtin_amdgcn_mfma_f32_16x16x32_bf16(qf[mf][0], kf0, s[mf], 0, 0, 0);
            s[mf] = __builtin_amdgcn_mfma_f32_16x16x32_bf16(qf[mf][1], kf1, s[mf], 0, 0, 0);
        }
        #pragma unroll
        for (int mf = 0; mf < 2; ++mf)
            #pragma unroll
            for (int r = 0; r < 4; ++r)
                S[mf * 16 + fq * 4 + r][wave * 16 + fr] = s[mf][r];
        __syncthreads();

        // ---- online softmax: 8 threads per row, 8 elems each ----
        {
            int row = tid >> 3, j = tid & 7;
            float pv[8];
            f32x4 x0 = *reinterpret_cast<const f32x4*>(&S[row][j * 8]);
            f32x4 x1 = *reinterpret_cast<const f32x4*>(&S[row][j * 8 + 4]);
            pv[0] = x0[0]; pv[1] = x0[1]; pv[2] = x0[2]; pv[3] = x0[3];
            pv[4] = x1[0]; pv[5] = x1[1]; pv[6] = x1[2]; pv[7] = x1[3];
            float mx = pv[0];
            #pragma unroll
            for (int c = 1; c < 8; ++c) mx = fmaxf(mx, pv[c]);
            mx = fmaxf(mx, __shfl_xor(mx, 1));
            mx = fmaxf(mx, __shfl_xor(mx, 2));
            mx = fmaxf(mx, __shfl_xor(mx, 4));
            float mold = mrow[row];
            float mnew = fmaxf(mold, mx);
            float sum = 0.f;
            #pragma unroll
            for (int c = 0; c < 8; ++c) { pv[c] = __expf(pv[c] - mnew); sum += pv[c]; }
            sum += __shfl_xor(sum, 1);
            sum += __shfl_xor(sum, 2);
            sum += __shfl_xor(sum, 4);
            u16x8 pb;
            #pragma unroll
            for (int c = 0; c < 8; ++c) pb[c] = f2b(pv[c]);
            *reinterpret_cast<u16x8*>(P + row * 64 + (j ^ (row & 7)) * 8) = pb;
            if (j == 0) {
                float e = __expf(mold - mnew);
                arow[row] = e;
                lrow[row] = lrow[row] * e + sum;
                mrow[row] = mnew;
            }
        }
        __syncthreads();

        // ---- PV: rescale + accumulate; wave covers O cols wave*16..+16 ----
        #pragma unroll
        for (int mf = 0; mf < 2; ++mf) {
            #pragma unroll
            for (int r = 0; r < 4; ++r)
                oacc[mf][r] *= arow[mf * 16 + fq * 4 + r];
            int prow = mf * 16 + fr;
            const u16* ap0 = P + prow * 64 + ((fq + 0) ^ (prow & 7)) * 8;
            const u16* ap1 = P + prow * 64 + ((fq + 4) ^ (prow & 7)) * 8;
            oacc[mf] = __builtin_amdgcn_mfma_f32_16x16x32_bf16(
                *reinterpret_cast<const bf16x8*>(ap0), vf0, oacc[mf], 0, 0, 0);
            oacc[mf] = __builtin_amdgcn_mfma_f32_16x16x32_bf16(
                *reinterpret_cast<const bf16x8*>(ap1), vf1, oacc[mf], 0, 0, 0);
        }
        kf0 = nk0; kf1 = nk1; vf0 = nv0; vf1 = nv1;
    }

    // ---- epilogue ----
    #pragma unroll
    for (int mf = 0; mf < 2; ++mf)
        #pragma unroll
        for (int r = 0; r < 4; ++r) {
            int row = mf * 16 + fq * 4 + r;
            float v = oacc[mf][r] / lrow[row];
            o[(size_t)(bb * NQ + qt * 32 + row) * DIM + h * HD + wave * 16 + fr] = f2b(v);
        }
}

// ---------------- launch ----------------
extern "C" void kernel_launch(void* const* d_in, const int* in_sizes, int n_in,
                              void* d_out, int out_size, void* d_ws, size_t ws_size,
                              hipStream_t stream) {
    const float* xq  = (const float*)d_in[0];
    const float* xkv = (const float*)d_in[1];
    const float* n1w = (const float*)d_in[2];
    const float* n1b = (const float*)d_in[3];
    const float* kvw = (const float*)d_in[4];
    const float* kvb = (const float*)d_in[5];
    const float* qw  = (const float*)d_in[6];
    const float* qb  = (const float*)d_in[7];
    const float* pjw = (const float*)d_in[8];
    const float* pjb = (const float*)d_in[9];
    const float* n2w = (const float*)d_in[10];
    const float* n2b = (const float*)d_in[11];
    const float* w1  = (const float*)d_in[12];
    const float* b1  = (const float*)d_in[13];
    const float* w2  = (const float*)d_in[14];
    const float* b2  = (const float*)d_in[15];
    float* xout = (float*)d_out;

    char* ws = (char*)d_ws;
    u16* xkv_b  = (u16*)(ws);              // 12582912 elems; later vt, later mlp hidden
    u16* kv_bf  = (u16*)(ws + 25165824);   // 25165824 elems
    u16* xn_bf  = (u16*)(ws + 75497472);   // 3145728 (reused as xn2)
    u16* q_bf   = (u16*)(ws + 81788928);   // 3145728
    u16* o_bf   = (u16*)(ws + 88080384);   // 3145728
    u16* wkv_bf = (u16*)(ws + 94371840);   // 1179648  (W^T)
    u16* wq_bf  = (u16*)(ws + 96731136);   // 589824   (W^T)
    u16* wpj_bf = (u16*)(ws + 97910784);   // 589824   (W^T)
    u16* w1_bf  = (u16*)(ws + 99090432);   // 2359296  (W^T)
    u16* w2_bf  = (u16*)(ws + 103809024);  // 2359296  (W^T)
    u16* vt     = xkv_b;                   // aliases: used between kv-gemm and mlp1
    u16* hid    = xkv_b;

    cast_bf16_kernel<<<dim3(6144), dim3(256), 0, stream>>>(xkv, xkv_b, 1572864);
    transpose_cast_kernel<<<dim3(24, 12), dim3(256), 0, stream>>>(kvw, wkv_bf, 768, 1536);
    transpose_cast_kernel<<<dim3(12, 12), dim3(256), 0, stream>>>(qw, wq_bf, 768, 768);
    transpose_cast_kernel<<<dim3(12, 12), dim3(256), 0, stream>>>(pjw, wpj_bf, 768, 768);
    transpose_cast_kernel<<<dim3(48, 12), dim3(256), 0, stream>>>(w1, w1_bf, 768, 3072);
    transpose_cast_kernel<<<dim3(12, 48), dim3(256), 0, stream>>>(w2, w2_bf, 3072, 768);

    // LN1: xq -> xn (bf16)
    ln_kernel<<<dim3(4096), dim3(256), 0, stream>>>(xq, n1w, n1b, xn_bf);
    // kv = xkv @ kv_w + kv_b  [16384, 1536] bf16
    gemm_kernel<0><<<dim3(12 * 128), dim3(256), 0, stream>>>(xkv_b, wkv_bf, kvb, nullptr, kv_bf, 16384, 1536, 768);
    // vt[bh][d][kv] (xkv_b no longer needed)
    transpose_v_kernel<<<dim3(64, 48), dim3(256), 0, stream>>>(kv_bf, vt);
    // q = (xn @ q_w + q_b) * 0.125  [4096, 768] bf16
    gemm_kernel<1><<<dim3(6 * 32), dim3(256), 0, stream>>>(xn_bf, wq_bf, qb, nullptr, q_bf, 4096, 768, 768);
    // attention -> o [4096, 768] bf16
    attn_kernel<<<dim3(1536), dim3(256), 0, stream>>>(q_bf, kv_bf, vt, o_bf);
    // x = xq + (o @ proj_w + proj_b)  -> d_out (f32)
    gemm_kernel<2><<<dim3(6 * 32), dim3(256), 0, stream>>>(o_bf, wpj_bf, pjb, xq, xout, 4096, 768, 768);
    // LN2: x -> xn2 (bf16)
    ln_kernel<<<dim3(4096), dim3(256), 0, stream>>>(xout, n2w, n2b, xn_bf);
    // h = gelu(xn2 @ w1 + b1)  [4096, 3072] bf16 (into xkv_b region; vt dead now)
    gemm_kernel<3><<<dim3(24 * 32), dim3(256), 0, stream>>>(xn_bf, w1_bf, b1, nullptr, hid, 4096, 3072, 768);
    // out = x + (h @ w2 + b2)  -> d_out (f32)
    gemm_kernel<2><<<dim3(6 * 32), dim3(256), 0, stream>>>(hid, w2_bf, b2, xout, xout, 4096, 768, 3072);
}

// Round 4
// 363.024 us; speedup vs baseline: 1.1938x; 1.1938x over previous
//
#include <hip/hip_runtime.h>
#include <hip/hip_bf16.h>
#include <math.h>

#define DIM 768
#define NH 12
#define HD 64
#define NQ 1024
#define NKV 4096
// 0.125 (HD^-0.5) * log2(e): softmax done in exp2 domain
#define QSCALE 0.18033688011112042f

typedef __attribute__((ext_vector_type(4))) float f32x4;
typedef __attribute__((ext_vector_type(8))) __bf16 bf16x8;
typedef __attribute__((ext_vector_type(8))) unsigned short u16x8;
typedef unsigned short u16;

typedef const __attribute__((address_space(1))) void* gas_t;
typedef __attribute__((address_space(3))) void* las_t;

__device__ __forceinline__ void gl16(const void* g, void* l) {
    __builtin_amdgcn_global_load_lds((gas_t)g, (las_t)l, 16, 0, 0);
}

__device__ __forceinline__ u16 f2b(float x) {
    __bf16 h = (__bf16)x;
    return __builtin_bit_cast(u16, h);
}

__device__ __forceinline__ f32x4 mfma16(const u16* a, const u16* b, f32x4 c) {
    bf16x8 av = *reinterpret_cast<const bf16x8*>(a);
    bf16x8 bv = *reinterpret_cast<const bf16x8*>(b);
    return __builtin_amdgcn_mfma_f32_16x16x32_bf16(av, bv, c, 0, 0, 0);
}

// ---------------- cast f32 -> bf16 (8 elems/thread) ----------------
__global__ __launch_bounds__(256) void cast_bf16_kernel(
    const float* __restrict__ in, u16* __restrict__ out, int n8)
{
    int i = blockIdx.x * 256 + threadIdx.x;
    if (i >= n8) return;
    const float4* p = reinterpret_cast<const float4*>(in) + (size_t)i * 2;
    float4 a = p[0], b = p[1];
    u16x8 o;
    o[0] = f2b(a.x); o[1] = f2b(a.y); o[2] = f2b(a.z); o[3] = f2b(a.w);
    o[4] = f2b(b.x); o[5] = f2b(b.y); o[6] = f2b(b.z); o[7] = f2b(b.w);
    reinterpret_cast<u16x8*>(out)[i] = o;
}

// ---------------- transpose+cast W[K][N] f32 -> Wt[N][K] bf16 ----------------
__global__ __launch_bounds__(256) void transpose_cast_kernel(
    const float* __restrict__ W, u16* __restrict__ Wt, int K, int N)
{
    __shared__ u16 T[64][72];
    int k0 = blockIdx.y * 64, n0 = blockIdx.x * 64;
    int tid = threadIdx.x;
    int r = tid >> 2, c = (tid & 3) * 16;
    const float* src = W + (size_t)(k0 + r) * N + n0 + c;
    #pragma unroll
    for (int j = 0; j < 16; j += 4) {
        float4 f = *reinterpret_cast<const float4*>(src + j);
        T[r][c + j + 0] = f2b(f.x); T[r][c + j + 1] = f2b(f.y);
        T[r][c + j + 2] = f2b(f.z); T[r][c + j + 3] = f2b(f.w);
    }
    __syncthreads();
    int d = tid >> 2, c2 = (tid & 3) * 16;
    u16x8 o0, o1;
    #pragma unroll
    for (int j = 0; j < 8; ++j) o0[j] = T[c2 + j][d];
    #pragma unroll
    for (int j = 0; j < 8; ++j) o1[j] = T[c2 + 8 + j][d];
    u16* dst = Wt + (size_t)(n0 + d) * K + k0 + c2;
    *reinterpret_cast<u16x8*>(dst) = o0;
    *reinterpret_cast<u16x8*>(dst + 8) = o1;
}

// ---------------- transpose V part of kv into vt[bh][d][kv] ----------------
__global__ __launch_bounds__(256) void transpose_v_kernel(
    const u16* __restrict__ kv, u16* __restrict__ vt)
{
    __shared__ u16 T[64][72];
    int kvt = blockIdx.x, bh = blockIdx.y;
    int bb = bh / NH, h = bh % NH;
    int tid = threadIdx.x;
    int r = tid >> 2, c = (tid & 3) * 16;
    const u16* src = kv + (size_t)(bb * NKV + kvt * 64 + r) * (2 * DIM) + DIM + h * HD + c;
    u16x8 v0 = *reinterpret_cast<const u16x8*>(src);
    u16x8 v1 = *reinterpret_cast<const u16x8*>(src + 8);
    #pragma unroll
    for (int j = 0; j < 8; ++j) T[r][c + j] = v0[j];
    #pragma unroll
    for (int j = 0; j < 8; ++j) T[r][c + 8 + j] = v1[j];
    __syncthreads();
    int d = tid >> 2, c2 = (tid & 3) * 16;
    u16x8 o0, o1;
    #pragma unroll
    for (int j = 0; j < 8; ++j) o0[j] = T[c2 + j][d];
    #pragma unroll
    for (int j = 0; j < 8; ++j) o1[j] = T[c2 + 8 + j][d];
    u16* dst = vt + ((size_t)bh * HD + d) * NKV + kvt * 64 + c2;
    *reinterpret_cast<u16x8*>(dst) = o0;
    *reinterpret_cast<u16x8*>(dst + 8) = o1;
}

// ---------------- LayerNorm (row = 768), f32 in -> bf16 out ----------------
__global__ __launch_bounds__(256) void ln_kernel(
    const float* __restrict__ x, const float* __restrict__ w,
    const float* __restrict__ b, u16* __restrict__ out)
{
    int row = blockIdx.x;
    const float* xr = x + (size_t)row * DIM;
    int tid = threadIdx.x;
    float v0 = xr[tid], v1 = xr[tid + 256], v2 = xr[tid + 512];
    float s = v0 + v1 + v2;
    float s2 = v0 * v0 + v1 * v1 + v2 * v2;
    for (int off = 1; off < 64; off <<= 1) {
        s += __shfl_xor(s, off);
        s2 += __shfl_xor(s2, off);
    }
    __shared__ float ss[4], ss2[4];
    int wid = tid >> 6, lane = tid & 63;
    if (lane == 0) { ss[wid] = s; ss2[wid] = s2; }
    __syncthreads();
    s = ss[0] + ss[1] + ss[2] + ss[3];
    s2 = ss2[0] + ss2[1] + ss2[2] + ss2[3];
    float mu = s * (1.0f / DIM);
    float var = s2 * (1.0f / DIM) - mu * mu;
    float r = rsqrtf(var + 1e-5f);
    u16* orow = out + (size_t)row * DIM;
    orow[tid]       = f2b((v0 - mu) * r * w[tid]       + b[tid]);
    orow[tid + 256] = f2b((v1 - mu) * r * w[tid + 256] + b[tid + 256]);
    orow[tid + 512] = f2b((v2 - mu) * r * w[tid + 512] + b[tid + 512]);
}

// ---------------- GEMM 128x128 tile, BK=64: C = A[M,K] @ Bt[N,K]^T + bias ----------------
// 1D grid, XCD-swizzled (blocks sharing an A-panel land on one XCD).
// Requires (M/128) % 8 == 0, K % 64 == 0.
// EPI 0: bf16 out   EPI 1: bf16 out * QSCALE   EPI 2: f32 out + res   EPI 3: bf16 gelu
template <int EPI>
__global__ __launch_bounds__(256) void gemm_kernel(
    const u16* __restrict__ A, const u16* __restrict__ Bt,
    const float* __restrict__ bias, const float* __restrict__ res,
    void* __restrict__ out, int M, int N, int K)
{
    __shared__ u16 As[8192]; // 128 rows x 64 k; row = 8 chunks of 16B, chunk XOR-swizzled by row&7
    __shared__ u16 Bs[8192];
    int p = blockIdx.x;
    int nbx = N >> 7;
    int ypx = (M >> 7) >> 3;
    int xcd = p & 7, slot = p >> 3;
    int by = xcd * ypx + slot / nbx;
    int bx = slot - (slot / nbx) * nbx;
    int n0 = bx * 128, m0 = by * 128;
    int tid = threadIdx.x, lane = tid & 63, wave = tid >> 6;
    int wm = (wave >> 1) * 64, wn = (wave & 1) * 64;
    f32x4 acc[4][4] = {};

    // staging: wave w, seg s (0..3): rows (w*4+s)*8 + (lane>>3), LDS chunk lane&7,
    // source k-chunk (lane&7) ^ (lane>>3)
    int robase = (lane >> 3);
    int c0 = ((lane & 7) ^ (lane >> 3)) * 8;
    const u16* ap[4]; const u16* bp[4];
    #pragma unroll
    for (int s = 0; s < 4; ++s) {
        int row = (wave * 4 + s) * 8 + robase;
        ap[s] = A + (size_t)(m0 + row) * K + c0;
        bp[s] = Bt + (size_t)(n0 + row) * K + c0;
    }
    u16* la = As + wave * 2048 + lane * 8;
    u16* lb = Bs + wave * 2048 + lane * 8;

    int fr = lane & 15, fq = lane >> 4;

    for (int k0 = 0; k0 < K; k0 += 64) {
        __syncthreads();
        #pragma unroll
        for (int s = 0; s < 4; ++s) {
            gl16(ap[s], la + s * 512);
            gl16(bp[s], lb + s * 512);
            ap[s] += 64; bp[s] += 64;
        }
        __syncthreads();
        #pragma unroll
        for (int ks = 0; ks < 2; ++ks)
            #pragma unroll
            for (int mf = 0; mf < 4; ++mf) {
                int arow = wm + mf * 16 + fr;
                const u16* a = As + arow * 64 + (((ks * 4 + fq) ^ (fr & 7)) * 8);
                #pragma unroll
                for (int nf = 0; nf < 4; ++nf) {
                    int brow = wn + nf * 16 + fr;
                    acc[mf][nf] = mfma16(a, Bs + brow * 64 + (((ks * 4 + fq) ^ (fr & 7)) * 8),
                                         acc[mf][nf]);
                }
            }
    }

    float* outf = reinterpret_cast<float*>(out);
    u16* outb = reinterpret_cast<u16*>(out);
    #pragma unroll
    for (int mf = 0; mf < 4; ++mf)
        #pragma unroll
        for (int nf = 0; nf < 4; ++nf)
            #pragma unroll
            for (int r = 0; r < 4; ++r) {
                int row = m0 + wm + mf * 16 + fq * 4 + r;
                int col = n0 + wn + nf * 16 + fr;
                size_t idx = (size_t)row * N + col;
                float v = acc[mf][nf][r] + bias[col];
                if constexpr (EPI == 0) {
                    outb[idx] = f2b(v);
                } else if constexpr (EPI == 1) {
                    outb[idx] = f2b(v * QSCALE);
                } else if constexpr (EPI == 2) {
                    outf[idx] = v + res[idx];
                } else {
                    float g = 0.5f * v * (1.0f + erff(v * 0.70710678118f));
                    outb[idx] = f2b(g);
                }
            }
}

// ---------------- Fused flash attention: QBLK=64, KVBLK=64, 4 waves ----------------
// grid 768 (1D), XCD-swizzled: 6 bh per XCD. Raw s_barrier + manual lgkmcnt so
// prefetched K/V register loads stay in flight across barriers (vmcnt waits at use).
// Softmax in exp2 domain (log2e folded into q scale).
__global__ __launch_bounds__(256) void attn_kernel(
    const u16* __restrict__ q, const u16* __restrict__ kv,
    const u16* __restrict__ vt, u16* __restrict__ o)
{
    int p = blockIdx.x;
    int xcd = p & 7, slot = p >> 3;        // 96 slots per XCD
    int bh = xcd * 6 + (slot >> 4);
    int qt = slot & 15;                    // 16 q-tiles of 64 rows
    int h = bh % NH, bb = bh / NH;

    __shared__ float S[64][68];
    __shared__ u16 P[64 * 64];             // 16B chunks swizzled by row&7
    __shared__ float mrow[64], lrow[64], arow[64];

    int tid = threadIdx.x, lane = tid & 63, wave = tid >> 6;
    int fr = lane & 15, fq = lane >> 4;

    bf16x8 qf[4][2];
    const u16* qbase = q + (size_t)(bb * NQ + qt * 64) * DIM + h * HD + fq * 8;
    #pragma unroll
    for (int mf = 0; mf < 4; ++mf)
        #pragma unroll
        for (int ks = 0; ks < 2; ++ks)
            qf[mf][ks] = *reinterpret_cast<const bf16x8*>(
                qbase + (size_t)(mf * 16 + fr) * DIM + ks * 32);

    if (tid < 64) { mrow[tid] = -1e30f; lrow[tid] = 0.f; }

    f32x4 oacc[4] = {};

    const u16* kptr = kv + (size_t)(bb * NKV + wave * 16 + fr) * (2 * DIM) + h * HD + fq * 8;
    const u16* vptr = vt + ((size_t)bh * HD + wave * 16 + fr) * NKV + fq * 8;

    bf16x8 kf0 = *reinterpret_cast<const bf16x8*>(kptr);
    bf16x8 kf1 = *reinterpret_cast<const bf16x8*>(kptr + 32);
    bf16x8 vf0 = *reinterpret_cast<const bf16x8*>(vptr);
    bf16x8 vf1 = *reinterpret_cast<const bf16x8*>(vptr + 32);

    for (int it = 0; it < NKV / 64; ++it) {
        // issue next-tile K/V loads; consumed next iter (vmcnt waits at use, not barrier)
        kptr += (size_t)64 * 2 * DIM;
        vptr += 64;
        bf16x8 nk0 = *reinterpret_cast<const bf16x8*>(kptr);
        bf16x8 nk1 = *reinterpret_cast<const bf16x8*>(kptr + 32);
        bf16x8 nv0 = *reinterpret_cast<const bf16x8*>(vptr);
        bf16x8 nv1 = *reinterpret_cast<const bf16x8*>(vptr + 32);

        // ---- QK^T: wave computes S[:, wave*16 .. +16] ----
        f32x4 s[4] = {};
        #pragma unroll
        for (int mf = 0; mf < 4; ++mf) {
            s[mf] = __builtin_amdgcn_mfma_f32_16x16x32_bf16(qf[mf][0], kf0, s[mf], 0, 0, 0);
            s[mf] = __builtin_amdgcn_mfma_f32_16x16x32_bf16(qf[mf][1], kf1, s[mf], 0, 0, 0);
        }
        #pragma unroll
        for (int mf = 0; mf < 4; ++mf)
            #pragma unroll
            for (int r = 0; r < 4; ++r)
                S[mf * 16 + fq * 4 + r][wave * 16 + fr] = s[mf][r];
        asm volatile("s_waitcnt lgkmcnt(0)" ::: "memory");
        __builtin_amdgcn_s_barrier();

        // ---- online softmax (exp2 domain): 4 threads per row, 16 elems each ----
        {
            int row = tid >> 2, j = tid & 3;
            const float* srow = &S[row][j * 16];
            float pv[16];
            #pragma unroll
            for (int qd = 0; qd < 4; ++qd) {
                f32x4 x = *reinterpret_cast<const f32x4*>(srow + qd * 4);
                pv[qd * 4 + 0] = x[0]; pv[qd * 4 + 1] = x[1];
                pv[qd * 4 + 2] = x[2]; pv[qd * 4 + 3] = x[3];
            }
            float mx = pv[0];
            #pragma unroll
            for (int c = 1; c < 16; ++c) mx = fmaxf(mx, pv[c]);
            mx = fmaxf(mx, __shfl_xor(mx, 1));
            mx = fmaxf(mx, __shfl_xor(mx, 2));
            float mold = mrow[row];
            float mnew = fmaxf(mold, mx);
            float sum = 0.f;
            #pragma unroll
            for (int c = 0; c < 16; ++c) { pv[c] = exp2f(pv[c] - mnew); sum += pv[c]; }
            sum += __shfl_xor(sum, 1);
            sum += __shfl_xor(sum, 2);
            u16x8 pb0, pb1;
            #pragma unroll
            for (int c = 0; c < 8; ++c) { pb0[c] = f2b(pv[c]); pb1[c] = f2b(pv[c + 8]); }
            int swz = row & 7;
            *reinterpret_cast<u16x8*>(P + row * 64 + ((j * 2) ^ swz) * 8) = pb0;
            *reinterpret_cast<u16x8*>(P + row * 64 + ((j * 2 + 1) ^ swz) * 8) = pb1;
            if (j == 0) {
                float e = exp2f(mold - mnew);
                arow[row] = e;
                lrow[row] = lrow[row] * e + sum;
                mrow[row] = mnew;
            }
        }
        asm volatile("s_waitcnt lgkmcnt(0)" ::: "memory");
        __builtin_amdgcn_s_barrier();

        // ---- PV: rescale + accumulate; wave covers O cols wave*16..+16 ----
        #pragma unroll
        for (int mf = 0; mf < 4; ++mf) {
            #pragma unroll
            for (int r = 0; r < 4; ++r)
                oacc[mf][r] *= arow[mf * 16 + fq * 4 + r];
            int prow = mf * 16 + fr;
            const u16* ap0 = P + prow * 64 + ((fq + 0) ^ (prow & 7)) * 8;
            const u16* ap1 = P + prow * 64 + ((fq + 4) ^ (prow & 7)) * 8;
            oacc[mf] = __builtin_amdgcn_mfma_f32_16x16x32_bf16(
                *reinterpret_cast<const bf16x8*>(ap0), vf0, oacc[mf], 0, 0, 0);
            oacc[mf] = __builtin_amdgcn_mfma_f32_16x16x32_bf16(
                *reinterpret_cast<const bf16x8*>(ap1), vf1, oacc[mf], 0, 0, 0);
        }
        // barrier before next iteration's S overwrite (softmax reads of S must be done;
        // PV's P reads complete before each wave arrives here)
        asm volatile("s_waitcnt lgkmcnt(0)" ::: "memory");
        __builtin_amdgcn_s_barrier();

        kf0 = nk0; kf1 = nk1; vf0 = nv0; vf1 = nv1;
    }

    // ---- epilogue ----
    #pragma unroll
    for (int mf = 0; mf < 4; ++mf)
        #pragma unroll
        for (int r = 0; r < 4; ++r) {
            int row = mf * 16 + fq * 4 + r;
            float v = oacc[mf][r] / lrow[row];
            o[(size_t)(bb * NQ + qt * 64 + row) * DIM + h * HD + wave * 16 + fr] = f2b(v);
        }
}

// ---------------- launch ----------------
extern "C" void kernel_launch(void* const* d_in, const int* in_sizes, int n_in,
                              void* d_out, int out_size, void* d_ws, size_t ws_size,
                              hipStream_t stream) {
    const float* xq  = (const float*)d_in[0];
    const float* xkv = (const float*)d_in[1];
    const float* n1w = (const float*)d_in[2];
    const float* n1b = (const float*)d_in[3];
    const float* kvw = (const float*)d_in[4];
    const float* kvb = (const float*)d_in[5];
    const float* qw  = (const float*)d_in[6];
    const float* qb  = (const float*)d_in[7];
    const float* pjw = (const float*)d_in[8];
    const float* pjb = (const float*)d_in[9];
    const float* n2w = (const float*)d_in[10];
    const float* n2b = (const float*)d_in[11];
    const float* w1  = (const float*)d_in[12];
    const float* b1  = (const float*)d_in[13];
    const float* w2  = (const float*)d_in[14];
    const float* b2  = (const float*)d_in[15];
    float* xout = (float*)d_out;

    char* ws = (char*)d_ws;
    u16* xkv_b  = (u16*)(ws);              // 12582912 elems; later vt, later mlp hidden
    u16* kv_bf  = (u16*)(ws + 25165824);   // 25165824 elems
    u16* xn_bf  = (u16*)(ws + 75497472);   // 3145728 (reused as xn2)
    u16* q_bf   = (u16*)(ws + 81788928);   // 3145728
    u16* o_bf   = (u16*)(ws + 88080384);   // 3145728
    u16* wkv_bf = (u16*)(ws + 94371840);   // 1179648  (W^T)
    u16* wq_bf  = (u16*)(ws + 96731136);   // 589824   (W^T)
    u16* wpj_bf = (u16*)(ws + 97910784);   // 589824   (W^T)
    u16* w1_bf  = (u16*)(ws + 99090432);   // 2359296  (W^T)
    u16* w2_bf  = (u16*)(ws + 103809024);  // 2359296  (W^T)
    u16* vt     = xkv_b;
    u16* hid    = xkv_b;

    cast_bf16_kernel<<<dim3(6144), dim3(256), 0, stream>>>(xkv, xkv_b, 1572864);
    transpose_cast_kernel<<<dim3(24, 12), dim3(256), 0, stream>>>(kvw, wkv_bf, 768, 1536);
    transpose_cast_kernel<<<dim3(12, 12), dim3(256), 0, stream>>>(qw, wq_bf, 768, 768);
    transpose_cast_kernel<<<dim3(12, 12), dim3(256), 0, stream>>>(pjw, wpj_bf, 768, 768);
    transpose_cast_kernel<<<dim3(48, 12), dim3(256), 0, stream>>>(w1, w1_bf, 768, 3072);
    transpose_cast_kernel<<<dim3(12, 48), dim3(256), 0, stream>>>(w2, w2_bf, 3072, 768);

    // LN1: xq -> xn (bf16)
    ln_kernel<<<dim3(4096), dim3(256), 0, stream>>>(xq, n1w, n1b, xn_bf);
    // kv = xkv @ kv_w + kv_b  [16384, 1536] bf16
    gemm_kernel<0><<<dim3(12 * 128), dim3(256), 0, stream>>>(xkv_b, wkv_bf, kvb, nullptr, kv_bf, 16384, 1536, 768);
    // vt[bh][d][kv]
    transpose_v_kernel<<<dim3(64, 48), dim3(256), 0, stream>>>(kv_bf, vt);
    // q = (xn @ q_w + q_b) * QSCALE  [4096, 768] bf16 (scale incl. log2e for exp2 softmax)
    gemm_kernel<1><<<dim3(6 * 32), dim3(256), 0, stream>>>(xn_bf, wq_bf, qb, nullptr, q_bf, 4096, 768, 768);
    // attention -> o [4096, 768] bf16
    attn_kernel<<<dim3(768), dim3(256), 0, stream>>>(q_bf, kv_bf, vt, o_bf);
    // x = xq + (o @ proj_w + proj_b)  -> d_out (f32)
    gemm_kernel<2><<<dim3(6 * 32), dim3(256), 0, stream>>>(o_bf, wpj_bf, pjb, xq, xout, 4096, 768, 768);
    // LN2: x -> xn2 (bf16)
    ln_kernel<<<dim3(4096), dim3(256), 0, stream>>>(xout, n2w, n2b, xn_bf);
    // h = gelu(xn2 @ w1 + b1)  [4096, 3072] bf16
    gemm_kernel<3><<<dim3(24 * 32), dim3(256), 0, stream>>>(xn_bf, w1_bf, b1, nullptr, hid, 4096, 3072, 768);
    // out = x + (h @ w2 + b2)  -> d_out (f32)
    gemm_kernel<2><<<dim3(6 * 32), dim3(256), 0, stream>>>(hid, w2_bf, b2, xout, xout, 4096, 768, 3072);
}